// Round 2
// baseline (1395.555 us; speedup 1.0000x reference)
//
#include <hip/hip_runtime.h>
#include <hip/hip_bf16.h>

#define T_ 768
#define A_ 24
#define S_ 576
#define Q_ 32
#define K_ 128
#define CA_ 128
#define CP_ 16

typedef const float* fp;

// ---------------- kernel 1: token_atoms_single_cond (T*A blocks, 128 thr) ----
__global__ void k_token_atoms(fp ref_ops, fp ref_mask, const int* ref_element,
                              fp ref_charge, const int* name_chars,
                              fp w_pos, fp w_maskw, fp w_elem, fp w_chg, fp w_name,
                              float* ws_tok)
{
    int ta = blockIdx.x;
    int c  = threadIdx.x;
    float p0 = ref_ops[ta*3+0];
    float p1 = ref_ops[ta*3+1];
    float p2 = ref_ops[ta*3+2];
    float m  = ref_mask[ta];
    int   e  = ref_element[ta];
    float chg= asinhf(ref_charge[ta]);
    float acc = p0*w_pos[0*CA_+c] + p1*w_pos[1*CA_+c] + p2*w_pos[2*CA_+c];
    acc += m * w_maskw[c];
    acc += w_elem[e*CA_+c];
    acc += chg * w_chg[c];
    #pragma unroll
    for (int j=0;j<4;j++){
        int v = name_chars[ta*4+j];
        acc += w_name[(j*64+v)*CA_+c];
    }
    ws_tok[ta*CA_+c] = acc * m;
}

// ---------------- kernel 2: tsc = LN(trunk_single) @ w_ts (T blocks, 128 thr)
__global__ void k_tsc(fp trunk_single, fp ln_s_scale, fp w_ts, float* ws_tsc)
{
    int t = blockIdx.x; int c = threadIdx.x;
    __shared__ float xh[384];
    __shared__ float red[128];
    float x0 = trunk_single[t*384 + c];
    float x1 = trunk_single[t*384 + 128 + c];
    float x2 = trunk_single[t*384 + 256 + c];
    red[c] = x0+x1+x2; __syncthreads();
    for (int off=64; off>0; off>>=1){ if (c<off) red[c]+=red[c+off]; __syncthreads(); }
    float mu = red[0] / 384.f;
    __syncthreads();
    float d0=x0-mu, d1=x1-mu, d2=x2-mu;
    red[c] = d0*d0+d1*d1+d2*d2; __syncthreads();
    for (int off=64; off>0; off>>=1){ if (c<off) red[c]+=red[c+off]; __syncthreads(); }
    float rs = rsqrtf(red[0]/384.f + 1e-5f);
    __syncthreads();
    xh[c]     = d0*rs*ln_s_scale[c];
    xh[c+128] = d1*rs*ln_s_scale[c+128];
    xh[c+256] = d2*rs*ln_s_scale[c+256];
    __syncthreads();
    float acc=0.f;
    for (int i=0;i<384;i++) acc += xh[i]*w_ts[i*CA_+c];
    ws_tsc[t*CA_+c]=acc;
}

// ---------------- kernel 3: queries_single_cond + row_act (S*Q blocks) -------
__global__ void k_queries(const float* ws_tok, const float* ws_tsc,
                          const int* a2q_idx, const int* a2q_mask,
                          const int* t2q_idx, const int* t2q_mask,
                          fp w_row,
                          float* ws_q, float* ws_rowa, float* out_q)
{
    int i = blockIdx.x; int c = threadIdx.x;
    __shared__ float r[128];
    float v = 0.f;
    if (a2q_mask[i]) v += ws_tok[a2q_idx[i]*CA_ + c];
    if (t2q_mask[i]) v += ws_tsc[t2q_idx[i]*CA_ + c];
    ws_q[i*CA_+c] = v;
    out_q[i*CA_+c] = v;
    r[c] = fmaxf(v, 0.f);
    __syncthreads();
    if (c < 16){
        float acc = 0.f;
        for (int cc=0; cc<128; cc++) acc += r[cc]*w_row[cc*16+c];
        ws_rowa[i*16+c] = acc;
    }
}

// ---------------- kernel 4: keys_single_cond + keys_mask + col_act (S*K) -----
__global__ void k_keys(const float* ws_q, const int* q2k_idx, const int* q2k_mask,
                       const int* queries_mask, fp w_col,
                       float* ws_cola, float* out_keys, float* out_kmask)
{
    int i = blockIdx.x; int c = threadIdx.x;
    __shared__ float r[128];
    int gi = q2k_idx[i]; int m = q2k_mask[i];
    float v = m ? ws_q[gi*CA_+c] : 0.f;
    out_keys[i*CA_+c] = v;
    if (c==0) out_kmask[i] = (m && queries_mask[gi]) ? 1.f : 0.f;
    r[c] = fmaxf(v, 0.f);
    __syncthreads();
    if (c < 16){
        float acc = 0.f;
        for (int cc=0; cc<128; cc++) acc += r[cc]*w_col[cc*16+c];
        ws_cola[i*16+c] = acc;
    }
}

// ---------------- kernel 5: tpc = LN(trunk_pair) @ w_tp (T*T blocks) ---------
__global__ void k_tpc(fp trunk_pair, fp ln_p_scale, fp w_tp, float* ws_tpc)
{
    int pid = blockIdx.x;         // t1*T + t2
    int tid = threadIdx.x;        // 0..127
    __shared__ float xh[128];
    __shared__ float red[128];
    __shared__ float wtp[2048];
    __shared__ float part[128];
    for (int i=tid; i<2048; i+=128) wtp[i] = w_tp[i];
    float x = trunk_pair[pid*128 + tid];
    red[tid]=x; __syncthreads();
    for (int off=64;off>0;off>>=1){ if(tid<off) red[tid]+=red[tid+off]; __syncthreads(); }
    float mu = red[0]/128.f; __syncthreads();
    float d = x-mu;
    red[tid]=d*d; __syncthreads();
    for (int off=64;off>0;off>>=1){ if(tid<off) red[tid]+=red[tid+off]; __syncthreads(); }
    float rs = rsqrtf(red[0]/128.f + 1e-5f);
    xh[tid] = d*rs*ln_p_scale[tid];
    __syncthreads();
    int j = tid & 15, chunk = tid >> 4;
    int c0 = chunk*16;
    float partial = 0.f;
    #pragma unroll
    for (int i2=0;i2<16;i2++) partial += xh[c0+i2]*wtp[(c0+i2)*16 + j];
    part[tid]=partial; __syncthreads();
    if (tid<16){
        float acc=0.f;
        #pragma unroll
        for (int ch=0; ch<8; ch++) acc += part[ch*16+tid];
        ws_tpc[pid*16+tid] = acc;
    }
}

// ---------------- kernel 6a/6b: geometry gathers -----------------------------
__global__ void k_qgeo(fp ref_ops, const int* ref_uid, const int* a2q_idx, const int* a2q_mask,
                       float* qpos, int* quid)
{
    int i = blockIdx.x*256 + threadIdx.x;
    if (i >= S_*Q_) return;
    int gi = a2q_idx[i]; int m = a2q_mask[i];
    qpos[i*3+0] = m ? ref_ops[gi*3+0] : 0.f;
    qpos[i*3+1] = m ? ref_ops[gi*3+1] : 0.f;
    qpos[i*3+2] = m ? ref_ops[gi*3+2] : 0.f;
    quid[i] = m ? ref_uid[gi] : 0;
}

__global__ void k_kgeo(const float* qpos, const int* ref_uid, const int* q2k_idx, const int* q2k_mask,
                       float* kpos, int* kuid)
{
    int i = blockIdx.x*256 + threadIdx.x;
    if (i >= S_*K_) return;
    int gi = q2k_idx[i]; int m = q2k_mask[i];
    kpos[i*3+0] = m ? qpos[gi*3+0] : 0.f;
    kpos[i*3+1] = m ? qpos[gi*3+1] : 0.f;
    kpos[i*3+2] = m ? qpos[gi*3+2] : 0.f;
    kuid[i] = m ? ref_uid[gi] : 0;   // NB: raw ref_space_uid flat, per reference
}

// ---------------- kernel 7: pair_act (one thread per (s,q,k)) ----------------
__global__ __launch_bounds__(256) void k_pair(
    const float* ws_rowa, const float* ws_cola, const float* ws_tpc,
    const float* qpos, const float* kpos, const int* quid, const int* kuid,
    const int* t2q_idx, const int* t2q_mask, const int* t2k_idx, const int* t2k_mask,
    fp w_off, fp w_dist, fp w_valid, fp w_m1, fp w_m2, fp w_m3,
    float* out_pair)
{
    __shared__ float sm1[256], sm2[256], sm3[256], soff[48], sdist[16], svalid[16];
    int tid = threadIdx.x;
    sm1[tid]=w_m1[tid]; sm2[tid]=w_m2[tid]; sm3[tid]=w_m3[tid];
    if (tid < 48) soff[tid]=w_off[tid];
    if (tid < 16){ sdist[tid]=w_dist[tid]; svalid[tid]=w_valid[tid]; }
    __syncthreads();
    int idx = blockIdx.x*256 + tid;  // S*Q*K = 2359296, exact multiple of 256
    int k  = idx & (K_-1);
    int sq = idx >> 7;               // s*Q + q
    int s  = sq >> 5;
    int sk = s*K_ + k;

    float p[16];
    const float4* ra4 = (const float4*)(ws_rowa + sq*16);
    const float4* ca4 = (const float4*)(ws_cola + sk*16);
    #pragma unroll
    for (int j4=0;j4<4;j4++){
        float4 a = ra4[j4], b = ca4[j4];
        p[j4*4+0]=a.x+b.x; p[j4*4+1]=a.y+b.y; p[j4*4+2]=a.z+b.z; p[j4*4+3]=a.w+b.w;
    }
    if (t2q_mask[sq] && t2k_mask[sk]){
        const float4* tp4 = (const float4*)(ws_tpc + (t2q_idx[sq]*T_ + t2k_idx[sk])*16);
        #pragma unroll
        for (int j4=0;j4<4;j4++){
            float4 v = tp4[j4];
            p[j4*4+0]+=v.x; p[j4*4+1]+=v.y; p[j4*4+2]+=v.z; p[j4*4+3]+=v.w;
        }
    }
    float ox = qpos[sq*3+0]-kpos[sk*3+0];
    float oy = qpos[sq*3+1]-kpos[sk*3+1];
    float oz = qpos[sq*3+2]-kpos[sk*3+2];
    if (quid[sq] == kuid[sk]){
        float invd = 1.f/(1.f + ox*ox+oy*oy+oz*oz);
        #pragma unroll
        for (int j=0;j<16;j++)
            p[j] += ox*soff[j] + oy*soff[16+j] + oz*soff[32+j] + invd*sdist[j] + svalid[j];
    }
    // MLP: p += relu(relu(relu(p)@m1)@m2)@m3
    float h[16], g[16];
    #pragma unroll
    for (int j=0;j<16;j++) h[j]=0.f;
    #pragma unroll
    for (int i=0;i<16;i++){ float r=fmaxf(p[i],0.f);
        #pragma unroll
        for (int j=0;j<16;j++) h[j] += r*sm1[i*16+j]; }
    #pragma unroll
    for (int j=0;j<16;j++) g[j]=0.f;
    #pragma unroll
    for (int i=0;i<16;i++){ float r=fmaxf(h[i],0.f);
        #pragma unroll
        for (int j=0;j<16;j++) g[j] += r*sm2[i*16+j]; }
    #pragma unroll
    for (int i=0;i<16;i++){ float r=fmaxf(g[i],0.f);
        #pragma unroll
        for (int j=0;j<16;j++) p[j] += r*sm3[i*16+j]; }

    float4* dst = (float4*)(out_pair + (long long)idx*16);
    #pragma unroll
    for (int j4=0;j4<4;j4++){
        float4 v; v.x=p[j4*4+0]; v.y=p[j4*4+1]; v.z=p[j4*4+2]; v.w=p[j4*4+3];
        dst[j4]=v;
    }
}

// ---------------- launch -----------------------------------------------------
extern "C" void kernel_launch(void* const* d_in, const int* in_sizes, int n_in,
                              void* d_out, int out_size, void* d_ws, size_t ws_size,
                              hipStream_t stream)
{
    fp trunk_single = (fp)d_in[0];
    fp trunk_pair   = (fp)d_in[1];
    fp ref_ops      = (fp)d_in[2];
    fp ref_mask     = (fp)d_in[3];
    const int* ref_element  = (const int*)d_in[4];
    fp ref_charge   = (fp)d_in[5];
    const int* name_chars   = (const int*)d_in[6];
    const int* ref_uid      = (const int*)d_in[7];
    const int* queries_mask = (const int*)d_in[8];
    const int* a2q_idx = (const int*)d_in[9];
    const int* a2q_mask= (const int*)d_in[10];
    const int* q2k_idx = (const int*)d_in[11];
    const int* q2k_mask= (const int*)d_in[12];
    const int* t2q_idx = (const int*)d_in[13];
    const int* t2q_mask= (const int*)d_in[14];
    const int* t2k_idx = (const int*)d_in[15];
    const int* t2k_mask= (const int*)d_in[16];
    fp w_pos  = (fp)d_in[17];
    fp w_maskw= (fp)d_in[18];
    fp w_elem = (fp)d_in[19];
    fp w_chg  = (fp)d_in[20];
    fp w_name = (fp)d_in[21];
    fp ln_s   = (fp)d_in[22];
    fp w_ts   = (fp)d_in[23];
    fp w_row  = (fp)d_in[24];
    fp w_col  = (fp)d_in[25];
    fp ln_p   = (fp)d_in[26];
    fp w_tp   = (fp)d_in[27];
    fp w_off  = (fp)d_in[28];
    fp w_dist = (fp)d_in[29];
    fp w_valid= (fp)d_in[30];
    fp w_m1   = (fp)d_in[31];
    fp w_m2   = (fp)d_in[32];
    fp w_m3   = (fp)d_in[33];

    float* out = (float*)d_out;
    float* out_q     = out;                                   // 2,359,296
    float* out_pair  = out + 2359296;                         // 37,748,736
    float* out_kmask = out + 2359296 + 37748736;              // 73,728
    float* out_keys  = out + 2359296 + 37748736 + 73728;      // 9,437,184

    float* ws = (float*)d_ws;                 // ~64.4 MB total f32
    float* ws_tok = ws;                       // T*A*CA    = 2,359,296
    float* ws_tsc = ws_tok + 2359296;         // T*CA      = 98,304
    float* ws_q   = ws_tsc + 98304;           // S*Q*CA    = 2,359,296
    float* ws_rowa= ws_q   + 2359296;         // S*Q*16    = 294,912
    float* ws_cola= ws_rowa+ 294912;          // S*K*16    = 1,179,648
    float* ws_tpc = ws_cola+ 1179648;         // T*T*16    = 9,437,184
    float* ws_qpos= ws_tpc + 9437184;         // S*Q*3     = 55,296
    float* ws_kpos= ws_qpos+ 55296;           // S*K*3     = 221,184
    int*   ws_quid= (int*)(ws_kpos + 221184); // S*Q       = 18,432
    int*   ws_kuid= ws_quid + 18432;          // S*K       = 73,728

    k_token_atoms<<<T_*A_, 128, 0, stream>>>(ref_ops, ref_mask, ref_element, ref_charge,
        name_chars, w_pos, w_maskw, w_elem, w_chg, w_name, ws_tok);
    k_tsc<<<T_, 128, 0, stream>>>(trunk_single, ln_s, w_ts, ws_tsc);
    k_queries<<<S_*Q_, 128, 0, stream>>>(ws_tok, ws_tsc, a2q_idx, a2q_mask, t2q_idx, t2q_mask,
        w_row, ws_q, ws_rowa, out_q);
    k_keys<<<S_*K_, 128, 0, stream>>>(ws_q, q2k_idx, q2k_mask, queries_mask, w_col,
        ws_cola, out_keys, out_kmask);
    k_tpc<<<T_*T_, 128, 0, stream>>>(trunk_pair, ln_p, w_tp, ws_tpc);
    k_qgeo<<<(S_*Q_+255)/256, 256, 0, stream>>>(ref_ops, ref_uid, a2q_idx, a2q_mask, ws_qpos, ws_quid);
    k_kgeo<<<(S_*K_+255)/256, 256, 0, stream>>>(ws_qpos, ref_uid, q2k_idx, q2k_mask, ws_kpos, ws_kuid);
    k_pair<<<(S_*Q_*K_)/256, 256, 0, stream>>>(ws_rowa, ws_cola, ws_tpc, ws_qpos, ws_kpos,
        ws_quid, ws_kuid, t2q_idx, t2q_mask, t2k_idx, t2k_mask,
        w_off, w_dist, w_valid, w_m1, w_m2, w_m3, out_pair);
}